// Round 3
// baseline (319.465 us; speedup 1.0000x reference)
//
#include <hip/hip_runtime.h>
#include <hip/hip_bf16.h>

typedef __attribute__((ext_vector_type(8))) short bf16x8;
typedef __attribute__((ext_vector_type(4))) float f32x4;

#define HD 256   // hidden size (K of the big GEMM)
#define NB 32    // batch
#define NT 4096  // timesteps
#define NE 8192  // edges per graph
#define N2 512   // 2*H (N of the big GEMM)

static __device__ __forceinline__ unsigned short f2bf(float f) {
  unsigned int u = __float_as_uint(f);
  u += 0x7fff + ((u >> 16) & 1);  // round-to-nearest-even
  return (unsigned short)(u >> 16);
}
static __device__ __forceinline__ short4 cvt4(float4 a) {
  return make_short4((short)f2bf(a.x), (short)f2bf(a.y),
                     (short)f2bf(a.z), (short)f2bf(a.w));
}
static __device__ __forceinline__ float fast_tanh(float x) {
  x = fminf(15.f, fmaxf(-15.f, x));
  float e = __expf(x + x);
  return (e - 1.f) * __builtin_amdgcn_rcpf(e + 1.f);
}

// Fused prep:
//  blocks 0..255   : cvecT[n][b] = b_attn[n] + hidden[b] . W_attn[n][0:256]
//  blocks 256..383 : Wbf[n*256+k] = bf16(W_attn[n][256+k])   (one-time convert)
__global__ __launch_bounds__(256) void prep(
    const float* __restrict__ hidden, const float* __restrict__ Wattn,
    const float* __restrict__ battn, float* __restrict__ cvecT,
    short* __restrict__ Wbf) {
  const int tid = threadIdx.x;
  if (blockIdx.x < 256) {
    __shared__ float Ws[64 * 260];
    __shared__ float Hs[HD];
    const int chunk = blockIdx.x & 7;
    const int b = blockIdx.x >> 3;
#pragma unroll
    for (int it = 0; it < 16; ++it) {
      int f = it * 1024 + tid * 4;
      int i = f >> 8, k = f & 255;
      float4 w4 = *(const float4*)(Wattn + (chunk * 64 + i) * N2 + k);
      *(float4*)&Ws[i * 260 + k] = w4;
    }
    if (tid < 64)
      *(float4*)&Hs[tid * 4] = *(const float4*)(hidden + b * HD + tid * 4);
    __syncthreads();
    const int nl = tid >> 2;
    const int kb = (tid & 3) * 64;
    float sum = 0.f;
#pragma unroll
    for (int z = 0; z < 64; z += 4) {
      float4 h4 = *(const float4*)&Hs[kb + z];
      float4 w4 = *(const float4*)&Ws[nl * 260 + kb + z];
      sum = fmaf(h4.x, w4.x, sum);
      sum = fmaf(h4.y, w4.y, sum);
      sum = fmaf(h4.z, w4.z, sum);
      sum = fmaf(h4.w, w4.w, sum);
    }
    sum += __shfl_xor(sum, 1, 64);
    sum += __shfl_xor(sum, 2, 64);
    if ((tid & 3) == 0)
      cvecT[(chunk * 64 + nl) * NB + b] = sum + battn[chunk * 64 + nl];
  } else {
    int f = (blockIdx.x - 256) * 1024 + tid * 4;  // 0..131071 = n*256+k
    int n = f >> 8, k = f & 255;
    float4 w4 = *(const float4*)(Wattn + n * N2 + HD + k);
    *(short4*)(Wbf + f) = cvt4(w4);
  }
}

// scores[b][t] = sum_n v[n]*tanh(cvecT[n][b] + enc_row . Wbf[n])
// 128 rows/block. B-chunk (64 cols x 256 k) lives in 128 VGPRs per wave;
// A staged in LDS with XOR swizzle (slot = (k>>3) ^ (r&31)) -> conflict-free
// ds_read_b128 (4-way broadcast). Wave covers cols {w*64, 256+w*64}.
__global__ __launch_bounds__(256, 2) void score_gemm(
    const float* __restrict__ enc, const short* __restrict__ Wbf,
    const float* __restrict__ cvecT, const float* __restrict__ vvec,
    float* __restrict__ scores) {
  __shared__ short As[128 * 256];  // 64 KB, swizzled
  __shared__ float part[4][128];
  const int tid = threadIdx.x;
  const int w = tid >> 6, lane = tid & 63, q = lane >> 4, m = lane & 15;
  const long row0 = (long)blockIdx.x * 128;

  ((float*)part)[tid] = 0.f;
  ((float*)part)[tid + 256] = 0.f;

  // ---- stage A (128 rows x 256 k) fp32 -> bf16, swizzled ----
  const float* src = enc + row0 * HD;
#pragma unroll
  for (int it = 0; it < 32; ++it) {
    int f = it * 1024 + tid * 4;
    float4 a4 = *(const float4*)(src + f);
    int r = f >> 8, k = f & 255;
    int slot = (k >> 3) ^ (r & 31);
    *(short4*)&As[(r * 32 + slot) * 8 + (k & 7)] = cvt4(a4);
  }
  __syncthreads();

#pragma unroll 1
  for (int cc = 0; cc < 2; ++cc) {
    const int nb = cc * 256 + w * 64;  // wave's col base
    bf16x8 breg[4][8];
    float vv[4];
    float4 cv[4][2];
#pragma unroll
    for (int c = 0; c < 4; ++c) {
      const int n = nb + c * 16 + m;
      const short* bp = Wbf + n * HD + q * 8;
#pragma unroll
      for (int kk = 0; kk < 8; ++kk) breg[c][kk] = *(const bf16x8*)(bp + kk * 32);
      vv[c] = vvec[n];
      cv[c][0] = *(const float4*)(cvecT + n * NB + q * 4);
      cv[c][1] = *(const float4*)(cvecT + n * NB + 16 + q * 4);
    }
#pragma unroll 1
    for (int rt = 0; rt < 8; ++rt) {
      const int r = rt * 16 + m;
      const int rx = r & 31;
      f32x4 acc[4] = {{0.f,0.f,0.f,0.f},{0.f,0.f,0.f,0.f},
                      {0.f,0.f,0.f,0.f},{0.f,0.f,0.f,0.f}};
#pragma unroll
      for (int kk = 0; kk < 8; ++kk) {
        bf16x8 a = *(const bf16x8*)&As[(r * 32 + ((kk * 4 + q) ^ rx)) * 8];
#pragma unroll
        for (int c = 0; c < 4; ++c)
          acc[c] = __builtin_amdgcn_mfma_f32_16x16x32_bf16(a, breg[c][kk], acc[c], 0, 0, 0);
      }
      const int p = rt & 1;
#pragma unroll
      for (int j = 0; j < 4; ++j) {
        // C/D layout: row (A-row) = rt*16 + 4q+j, col (B-row) = n(c,m)
        float e = fast_tanh(acc[0][j] + cv[0][p][j]) * vv[0]
                + fast_tanh(acc[1][j] + cv[1][p][j]) * vv[1]
                + fast_tanh(acc[2][j] + cv[2][p][j]) * vv[2]
                + fast_tanh(acc[3][j] + cv[3][p][j]) * vv[3];
        e += __shfl_xor(e, 1, 64);
        e += __shfl_xor(e, 2, 64);
        e += __shfl_xor(e, 4, 64);
        e += __shfl_xor(e, 8, 64);  // sum over the 16 m-lanes
        if (m == 0) part[w][rt * 16 + 4 * q + j] += e;
      }
    }
  }
  __syncthreads();
  if (tid < 128) {
    const long r = row0 + tid;  // flat row = t*NB + b
    scores[(r & 31) * NT + (r >> 5)] =
        part[0][tid] + part[1][tid] + part[2][tid] + part[3][tid];
  }
}

// softmax over T per batch row; writes wn = 0.1*softmax in-place; zeroes out[b]
__global__ __launch_bounds__(1024) void softmax_norm(
    float* __restrict__ sc, float* __restrict__ out) {
  __shared__ float rtmp[16];
  __shared__ float rres;
  const int b = blockIdx.x;
  const int tid = threadIdx.x;
  const int wid = tid >> 6, lane = tid & 63;
  float s[4];
  float mx = -1e30f;
#pragma unroll
  for (int p = 0; p < 4; ++p) {
    s[p] = sc[b * NT + tid + p * 1024];
    mx = fmaxf(mx, s[p]);
  }
#pragma unroll
  for (int d = 32; d >= 1; d >>= 1) mx = fmaxf(mx, __shfl_xor(mx, d, 64));
  if (lane == 0) rtmp[wid] = mx;
  __syncthreads();
  if (tid == 0) {
    float mm = rtmp[0];
#pragma unroll
    for (int i = 1; i < 16; ++i) mm = fmaxf(mm, rtmp[i]);
    rres = mm;
  }
  __syncthreads();
  mx = rres;
  float sm = 0.f;
#pragma unroll
  for (int p = 0; p < 4; ++p) {
    s[p] = __expf(s[p] - mx);
    sm += s[p];
  }
#pragma unroll
  for (int d = 32; d >= 1; d >>= 1) sm += __shfl_xor(sm, d, 64);
  if (lane == 0) rtmp[wid] = sm;
  __syncthreads();
  if (tid == 0) {
    float tt = 0.f;
#pragma unroll
    for (int i = 0; i < 16; ++i) tt += rtmp[i];
    rres = tt;
  }
  __syncthreads();
  const float scale = 0.1f / rres;
#pragma unroll
  for (int p = 0; p < 4; ++p) {
    int i = tid + p * 1024;
    sc[b * NT + i] = s[p] * scale;  // wn
    out[b * NT + i] = 0.f;          // zero-init for scatter
  }
}

// out[b][dst] += wn[b][src] for edges with dst != src+1 (global atomics)
__global__ __launch_bounds__(512) void scatter(
    const float* __restrict__ wn, const int* __restrict__ esrc,
    const int* __restrict__ edst, float* __restrict__ out) {
  const int b = blockIdx.x >> 4;
  const int e = (blockIdx.x & 15) * 512 + threadIdx.x;
  const int ss = esrc[b * NE + e];
  const int dd = edst[b * NE + e];
  if (dd != ss + 1) atomicAdd(out + b * NT + dd, wn[b * NT + ss]);
}

extern "C" void kernel_launch(void* const* d_in, const int* in_sizes, int n_in,
                              void* d_out, int out_size, void* d_ws, size_t ws_size,
                              hipStream_t stream) {
  const float* hidden = (const float*)d_in[0];
  const float* enc    = (const float*)d_in[1];
  const int*   esrc   = (const int*)d_in[2];
  const int*   edst   = (const int*)d_in[3];
  const float* Wattn  = (const float*)d_in[4];
  const float* battn  = (const float*)d_in[5];
  const float* vvec   = (const float*)d_in[6];
  float* out = (float*)d_out;

  char* ws = (char*)d_ws;
  float* cvecT  = (float*)ws;                    // 512*32*4   = 64 KB
  short* Wbf    = (short*)(ws + 65536);          // 512*256*2  = 256 KB
  float* scores = (float*)(ws + 65536 + 262144); // 32*4096*4  = 512 KB

  prep<<<384, 256, 0, stream>>>(hidden, Wattn, battn, cvecT, Wbf);
  score_gemm<<<(NB * NT) / 128, 256, 0, stream>>>(enc, Wbf, cvecT, vvec, scores);
  softmax_norm<<<NB, 1024, 0, stream>>>(scores, out);
  scatter<<<512, 512, 0, stream>>>(scores, esrc, edst, out);
}